// Round 1
// baseline (34912.588 us; speedup 1.0000x reference)
//
#include <hip/hip_runtime.h>
#include <hip/hip_bf16.h>

// GRU with softmax gates. SEQ=512, BS=128, IN=512, H=1024, D=1536.
// Round 0: correctness-first MFMA implementation.
//   - bf16 GEMMs (MFMA 16x16x32), fp32 master h.
//   - weights pre-transposed to [N][K] bf16 so B-fragments are 16B contiguous.
//   - 3 kernels per step x 512 steps, launched in a loop (graph-captured).
// Workspace need: ~76 MiB.

#define SEQ 512
#define BS 128
#define IN_DIM 512
#define H_DIM 1024
#define DTOT 1536   // H_DIM + IN_DIM
#define NZR 2048    // 2*H_DIM

typedef __attribute__((ext_vector_type(8))) short bfrag;   // 8 x bf16 (4 VGPRs)
typedef __attribute__((ext_vector_type(4))) float facc;    // 4 x f32

__device__ __forceinline__ unsigned short f2bf(float f) {
    unsigned int u = __float_as_uint(f);
    unsigned int r = (u + 0x7FFFu + ((u >> 16) & 1u)) >> 16;
    return (unsigned short)r;
}

// ---------------- one-time converts ----------------

// Build wzr_t [2048][1536] and wh_t [1024][1536] (bf16, n-major) from
// Wz/Wr/Wh fp32 [1536][1024] (k-major).
__global__ void cvt_w(const float* __restrict__ Wz, const float* __restrict__ Wr,
                      const float* __restrict__ Wh,
                      unsigned short* __restrict__ wzr, unsigned short* __restrict__ wh) {
    size_t i = (size_t)blockIdx.x * 256 + threadIdx.x;
    if (i >= (size_t)3072 * DTOT) return;
    int k = (int)(i % DTOT);
    int n = (int)(i / DTOT);
    float v;
    if (n < 1024)       v = Wz[(size_t)k * H_DIM + n];
    else if (n < 2048)  v = Wr[(size_t)k * H_DIM + (n - 1024)];
    else                v = Wh[(size_t)k * H_DIM + (n - 2048)];
    unsigned short b = f2bf(v);
    if (n < 2048) wzr[(size_t)n * DTOT + k] = b;
    else          wh[(size_t)(n - 2048) * DTOT + k] = b;
}

// x fp32 -> bf16, 4 elems/thread.
__global__ void cvt_x(const float4* __restrict__ x, unsigned long long* __restrict__ xb) {
    size_t i = (size_t)blockIdx.x * 256 + threadIdx.x;
    if (i >= (size_t)SEQ * BS * IN_DIM / 4) return;
    float4 v = x[i];
    unsigned long long p = (unsigned long long)f2bf(v.x)
                         | ((unsigned long long)f2bf(v.y) << 16)
                         | ((unsigned long long)f2bf(v.z) << 32)
                         | ((unsigned long long)f2bf(v.w) << 48);
    xb[i] = p;
}

__global__ void init_h(const float* __restrict__ h0, float* __restrict__ hf,
                       unsigned short* __restrict__ hb) {
    int i = blockIdx.x * 256 + threadIdx.x;
    if (i >= BS * H_DIM) return;
    float v = h0[i];
    hf[i] = v;
    hb[i] = f2bf(v);
}

// ---------------- per-step kernels ----------------

// pre[128][2048] = [h|x] @ Wzr + bias. A: rows=batch, cols=k (k<1024 from hb, else xb).
// Tiles 64x64, 4 waves each 64x16. No LDS; direct global fragment loads.
__global__ __launch_bounds__(256) void gemm_zr(
    const unsigned short* __restrict__ hb,    // [128][1024]
    const unsigned short* __restrict__ xb,    // [128][512] (step t)
    const unsigned short* __restrict__ wt,    // [2048][1536]
    const float* __restrict__ bz, const float* __restrict__ br,
    float* __restrict__ pre) {
    const int lane = threadIdx.x & 63;
    const int wid  = threadIdx.x >> 6;
    const int nBase = blockIdx.x * 64 + wid * 16;
    const int mBase = blockIdx.y * 64;
    const int lm = lane & 15;
    const int kq = lane >> 4;
    facc acc[4];
    #pragma unroll
    for (int i = 0; i < 4; ++i) acc[i] = (facc){0.f, 0.f, 0.f, 0.f};
    const unsigned short* wrow = wt + (size_t)(nBase + lm) * DTOT + kq * 8;
    #pragma unroll 4
    for (int kc = 0; kc < DTOT; kc += 32) {
        const unsigned short* asrc;
        int astride;
        if (kc < 1024) { asrc = hb + kc;          astride = H_DIM; }
        else           { asrc = xb + (kc - 1024); astride = IN_DIM; }
        bfrag b = *(const bfrag*)(wrow + kc);
        #pragma unroll
        for (int mt = 0; mt < 4; ++mt) {
            bfrag a = *(const bfrag*)(asrc + (size_t)(mBase + mt * 16 + lm) * astride + kq * 8);
            acc[mt] = __builtin_amdgcn_mfma_f32_16x16x32_bf16(a, b, acc[mt], 0, 0, 0);
        }
    }
    const int col = nBase + lm;
    const float bias = (col < 1024) ? bz[col] : br[col - 1024];
    #pragma unroll
    for (int mt = 0; mt < 4; ++mt) {
        #pragma unroll
        for (int r = 0; r < 4; ++r) {
            int row = mBase + mt * 16 + kq * 4 + r;
            pre[(size_t)row * NZR + col] = acc[mt][r] + bias;
        }
    }
}

// Per batch row: z = softmax(pre[:1024]); r = softmax(pre[1024:]); rh = bf16(r*h).
__global__ __launch_bounds__(256) void softmax_rh(
    const float* __restrict__ pre, const float* __restrict__ hf,
    float* __restrict__ z, unsigned short* __restrict__ rh) {
    const int b = blockIdx.x;
    const int tid = threadIdx.x;
    const int lane = tid & 63, wid = tid >> 6;
    const float* prow = pre + (size_t)b * NZR;
    float zl[4], rl[4];
    float mz = -1e30f, mr = -1e30f;
    #pragma unroll
    for (int j = 0; j < 4; ++j) {
        int n = tid + j * 256;
        zl[j] = prow[n];
        rl[j] = prow[1024 + n];
        mz = fmaxf(mz, zl[j]); mr = fmaxf(mr, rl[j]);
    }
    #pragma unroll
    for (int off = 32; off; off >>= 1) {
        mz = fmaxf(mz, __shfl_down(mz, off, 64));
        mr = fmaxf(mr, __shfl_down(mr, off, 64));
    }
    __shared__ float sm[8];
    if (lane == 0) { sm[wid] = mz; sm[4 + wid] = mr; }
    __syncthreads();
    mz = fmaxf(fmaxf(sm[0], sm[1]), fmaxf(sm[2], sm[3]));
    mr = fmaxf(fmaxf(sm[4], sm[5]), fmaxf(sm[6], sm[7]));
    float sz = 0.f, sr = 0.f;
    #pragma unroll
    for (int j = 0; j < 4; ++j) {
        zl[j] = expf(zl[j] - mz); rl[j] = expf(rl[j] - mr);
        sz += zl[j]; sr += rl[j];
    }
    #pragma unroll
    for (int off = 32; off; off >>= 1) {
        sz += __shfl_down(sz, off, 64);
        sr += __shfl_down(sr, off, 64);
    }
    __shared__ float ss[8];
    if (lane == 0) { ss[wid] = sz; ss[4 + wid] = sr; }
    __syncthreads();
    sz = ss[0] + ss[1] + ss[2] + ss[3];
    sr = ss[4] + ss[5] + ss[6] + ss[7];
    const float inz = 1.0f / sz, inr = 1.0f / sr;
    #pragma unroll
    for (int j = 0; j < 4; ++j) {
        int n = tid + j * 256;
        size_t idx = (size_t)b * H_DIM + n;
        z[idx] = zl[j] * inz;
        rh[idx] = f2bf(rl[j] * inr * hf[idx]);
    }
}

// pre_h = [r*h|x] @ Wh + bh; h_new = h + z*(tanh(pre_h) - h); writes h (f32+bf16) and out[t].
__global__ __launch_bounds__(256) void gemm_h(
    const unsigned short* __restrict__ rh,    // [128][1024]
    const unsigned short* __restrict__ xb,    // [128][512] (step t)
    const unsigned short* __restrict__ wt,    // [1024][1536]
    const float* __restrict__ bh,
    const float* __restrict__ z,
    float* __restrict__ hf, unsigned short* __restrict__ hb,
    float* __restrict__ out) {
    const int lane = threadIdx.x & 63;
    const int wid  = threadIdx.x >> 6;
    const int nBase = blockIdx.x * 64 + wid * 16;
    const int mBase = blockIdx.y * 64;
    const int lm = lane & 15;
    const int kq = lane >> 4;
    facc acc[4];
    #pragma unroll
    for (int i = 0; i < 4; ++i) acc[i] = (facc){0.f, 0.f, 0.f, 0.f};
    const unsigned short* wrow = wt + (size_t)(nBase + lm) * DTOT + kq * 8;
    #pragma unroll 4
    for (int kc = 0; kc < DTOT; kc += 32) {
        const unsigned short* asrc;
        int astride;
        if (kc < 1024) { asrc = rh + kc;          astride = H_DIM; }
        else           { asrc = xb + (kc - 1024); astride = IN_DIM; }
        bfrag b = *(const bfrag*)(wrow + kc);
        #pragma unroll
        for (int mt = 0; mt < 4; ++mt) {
            bfrag a = *(const bfrag*)(asrc + (size_t)(mBase + mt * 16 + lm) * astride + kq * 8);
            acc[mt] = __builtin_amdgcn_mfma_f32_16x16x32_bf16(a, b, acc[mt], 0, 0, 0);
        }
    }
    const int col = nBase + lm;
    const float bias = bh[col];
    #pragma unroll
    for (int mt = 0; mt < 4; ++mt) {
        #pragma unroll
        for (int r = 0; r < 4; ++r) {
            int row = mBase + mt * 16 + kq * 4 + r;
            size_t idx = (size_t)row * H_DIM + col;
            float th = tanhf(acc[mt][r] + bias);
            float zv = z[idx];
            float hv = hf[idx];
            float hn = fmaf(zv, th - hv, hv);
            hf[idx] = hn;
            hb[idx] = f2bf(hn);
            out[idx] = hn;
        }
    }
}

// ---------------- launch ----------------

extern "C" void kernel_launch(void* const* d_in, const int* in_sizes, int n_in,
                              void* d_out, int out_size, void* d_ws, size_t ws_size,
                              hipStream_t stream) {
    const float* x  = (const float*)d_in[0];
    const float* h0 = (const float*)d_in[1];
    const float* Wz = (const float*)d_in[2];
    const float* bz = (const float*)d_in[3];
    const float* Wr = (const float*)d_in[4];
    const float* br = (const float*)d_in[5];
    const float* Wh = (const float*)d_in[6];
    const float* bh = (const float*)d_in[7];
    float* out = (float*)d_out;

    char* base = (char*)d_ws;
    unsigned short* wzr_t  = (unsigned short*)(base);                 //  6,291,456 B
    unsigned short* wh_t   = (unsigned short*)(base + 6291456);       //  3,145,728 B
    unsigned short* x_bf16 = (unsigned short*)(base + 9437184);       // 67,108,864 B
    float*          h_f32  = (float*)         (base + 76546048);      //    524,288 B
    unsigned short* h_bf16 = (unsigned short*)(base + 77070336);      //    262,144 B
    unsigned short* rh_b   = (unsigned short*)(base + 77332480);      //    262,144 B
    float*          pre_zr = (float*)         (base + 77594624);      //  1,048,576 B
    float*          z_f32  = (float*)         (base + 78643200);      //    524,288 B
    // total 79,167,488 B (~75.5 MiB)

    cvt_w<<<(3072 * DTOT + 255) / 256, 256, 0, stream>>>(Wz, Wr, Wh, wzr_t, wh_t);
    cvt_x<<<((SEQ * BS * IN_DIM / 4) + 255) / 256, 256, 0, stream>>>(
        (const float4*)x, (unsigned long long*)x_bf16);
    init_h<<<(BS * H_DIM + 255) / 256, 256, 0, stream>>>(h0, h_f32, h_bf16);

    for (int t = 0; t < SEQ; ++t) {
        const unsigned short* xb_t = x_bf16 + (size_t)t * BS * IN_DIM;
        float* out_t = out + (size_t)t * BS * H_DIM;
        gemm_zr<<<dim3(NZR / 64, BS / 64), 256, 0, stream>>>(
            h_bf16, xb_t, wzr_t, bz, br, pre_zr);
        softmax_rh<<<BS, 256, 0, stream>>>(pre_zr, h_f32, z_f32, rh_b);
        gemm_h<<<dim3(H_DIM / 64, BS / 64), 256, 0, stream>>>(
            rh_b, xb_t, wh_t, bh, z_f32, h_f32, h_bf16, out_t);
    }
}